// Round 1
// 911.399 us; speedup vs baseline: 2.2103x; 2.2103x over previous
//
#include <hip/hip_runtime.h>
#include <math.h>

// ---------------- problem dims ----------------
constexpr int Bb = 128, Tt = 256, Dd = 64, Hh = 512, Cc = 10;
constexpr float MISSINGV = 128.0f;

#define NBLK 256
#define NTHR 256

typedef float v4f __attribute__((ext_vector_type(4)));
typedef float f4 __attribute__((ext_vector_type(4)));
typedef _Float16 half8 __attribute__((ext_vector_type(8)));
typedef _Float16 half4 __attribute__((ext_vector_type(4)));

// ---------------- workspace layout (bytes) ----------------
constexpr size_t WS_PLOSS = 128;                    // float pred-loss accumulator
constexpr size_t WS_REG   = 192;                    // float reg accumulator
constexpr size_t WS_FLG   = 256;                    // 8 groups x 512 B per-BLOCK epoch flags (32 words used)
constexpr size_t WS_H     = 8192;                   // h fp16 ping-pong [2][128][512] = 262144 B
constexpr size_t WS_WT16  = WS_H + 262144;          // W^T fp16 [64 d][512 k] = 65536
constexpr size_t WS_BM16  = WS_WT16 + 65536;        // per-ht B fp16 [32][64 n][576 k] = 2359296

// ---------------- LDS layout ----------------
constexpr int XSTR = 72;                            // halfs per xin row (64 + pad)
constexpr int PSTR = 68;                            // floats per predS/zS row
constexpr int HSTR = 520;                           // halfs per hS row (512 + 8 pad -> row stride 1040 B)
constexpr size_t SM_XIN  = 0;                       // xin fp16 [16][72] = 2304 B
constexpr size_t SM_PRED = 2304;                    // predS [16][68] f32 = 4352 B
constexpr size_t SM_ZS   = 6656;                    // zS [16][68] f32 = 4352 B
constexpr size_t SM_RED  = 11008;                   // 64 B
constexpr size_t SM_H    = 11072;                   // hS fp16 [16][520] = 16640 B
constexpr size_t SM_TOTAL= SM_H + (size_t)16 * HSTR * 2;   // 27712 B

// ---- IC-coherent vector load with immediate offset (sc0 sc1: bypass L1+L2) ----
#define CLD4O(dst, base, OFF) \
    asm volatile("global_load_dwordx4 %0, %1, off offset:" OFF " sc0 sc1" : "=v"(dst) : "v"(base))
#define CWAIT4(a0,a1,a2,a3) \
    asm volatile("s_waitcnt vmcnt(0)" : "+v"(a0),"+v"(a1),"+v"(a2),"+v"(a3) :: "memory")

__device__ __forceinline__ unsigned coh_ld_u(const unsigned* p) {
    return __hip_atomic_load(p, __ATOMIC_RELAXED, __HIP_MEMORY_SCOPE_AGENT);
}
__device__ __forceinline__ void coh_st_u(unsigned* p, unsigned v) {
    __hip_atomic_store(p, v, __ATOMIC_RELAXED, __HIP_MEMORY_SCOPE_AGENT);
}
// fast, saturation-safe gate functions (abs err ~1e-6, fine vs 5.6e-2 threshold)
__device__ __forceinline__ float fsig(float v)  { return __builtin_amdgcn_rcpf(1.f + __expf(-v)); }
__device__ __forceinline__ float ftanh(float v) { float e = __expf(2.f*v); return 1.f - 2.f*__builtin_amdgcn_rcpf(e+1.f); }

// ---------------- weight prep: fp16 pack ----------------
// WT16[d][k] = W[k][d]; BM16[ht][n][k]: n=u*4+g, col=g*512+ht*16+u;
// k<64 -> kernel[k][col], else rkernel[k-64][col]
__global__ void prep_weights(const float* __restrict__ rk, const float* __restrict__ kern,
                             const float* __restrict__ W,
                             _Float16* __restrict__ bm, _Float16* __restrict__ wt) {
    int o = blockIdx.x * 256 + threadIdx.x;
    if (o < 32 * 64 * 576) {
        int ht = o / 36864, rem = o % 36864, n = rem / 576, k = rem % 576;
        int u = n >> 2, g = n & 3, col = g * 512 + ht * 16 + u;
        float v = (k < 64) ? kern[k * 2048 + col] : rk[(k - 64) * 2048 + col];
        bm[o] = (_Float16)v;
    }
    if (o < 64 * 512) {
        int d = o >> 9, k = o & 511;
        wt[o] = (_Float16)W[k * 64 + d];
    }
}

// ---------------- persistent scan kernel ----------------
__launch_bounds__(NTHR, 1)
__global__ void ajrnn_persistent(
    const float* __restrict__ x, const float* __restrict__ tgt, const float* __restrict__ msk,
    const float* __restrict__ W, const float* __restrict__ bias,
    const float* __restrict__ kern, const float* __restrict__ rkern, const float* __restrict__ lbias,
    const float* __restrict__ dW, const float* __restrict__ db,
    unsigned char* __restrict__ ws)
{
    __shared__ __align__(16) unsigned char smem[SM_TOTAL];
    _Float16* xinS = (_Float16*)(smem + SM_XIN);
    float* predS = (float*)(smem + SM_PRED);
    float* zS    = (float*)(smem + SM_ZS);
    float* redsc = (float*)(smem + SM_RED);
    _Float16* hS = (_Float16*)(smem + SM_H);

    float* ploss_acc = (float*)(ws + WS_PLOSS);
    float* reg_acc   = (float*)(ws + WS_REG);
    _Float16* h16h   = (_Float16*)(ws + WS_H);      // [2][128][512] halfs
    unsigned* h16u   = (unsigned*)(ws + WS_H);      // same, as packed uints [2][128][256]
    const _Float16* WT16g = (const _Float16*)(ws + WS_WT16);
    const _Float16* BM16g = (const _Float16*)(ws + WS_BM16);

    const int tid = threadIdx.x;
    const int bid = blockIdx.x;
    const int rt = bid >> 5, ht = bid & 31;         // 8 row-groups x 32 hidden-tiles
    const int r0 = rt * 16, j0 = ht * 16;
    const int wave = tid >> 6, lane = tid & 63;
    const int lm = lane & 15;                       // MFMA A-row m / B n-within-tile
    const int kq = (lane >> 4) * 8;                 // MFMA quad k offset
    const int cn = wave * 16 + lm;                  // this lane's global col (0..63)
    const int cr = tid >> 4, cu = tid & 15;         // gate-phase row/unit

    // ---- per-BLOCK epoch flags: flg[ht] == v  means block (rt,ht) has stored its
    // rows of h[v] (all 4 waves vmcnt-drained, then __syncthreads, then one store)
    // AND finished reading h[v-1].  All 32 flags >= t  =>  h[t] fully available
    // AND the h[t-1] buffer is dead.  Single writer per word, monotone, no atomics.
    unsigned* flg = (unsigned*)(ws + WS_FLG + (size_t)rt * 512);
    auto flag_wait = [&](unsigned t) {
        for (;;) {
            unsigned f = coh_ld_u(&flg[lane & 31]);
            if (__all((int)(f >= t))) break;
            __builtin_amdgcn_s_sleep(1);
        }
    };

    // per-thread constants
    const float bvp = bias[cn];
    const int ju = j0 + cu;
    const float lb0 = lbias[ju], lb1 = lbias[Hh + ju], lb2 = lbias[2*Hh + ju], lb3 = lbias[3*Hh + ju];

    // ---- L2 regularization ----
    {
        float rs = 0.f;
        const float* arrs[7] = {W, bias, kern, rkern, lbias, dW, db};
        const int lens[7] = {Hh*Dd, Dd, Dd*4*Hh, Hh*4*Hh, 4*Hh, Hh*Cc, Cc};
        for (int a = 0; a < 7; ++a) {
            const float* p = arrs[a]; const int n = lens[a];
            for (int i = bid * NTHR + tid; i < n; i += NBLK * NTHR) { float v = p[i]; rs += v * v; }
        }
        #pragma unroll
        for (int off = 32; off > 0; off >>= 1) rs += __shfl_down(rs, off);
        if (lane == 0) redsc[wave] = rs;
        __syncthreads();
        if (tid == 0) atomicAdd(reg_acc, redsc[0] + redsc[1] + redsc[2] + redsc[3]);
        __syncthreads();
    }

    // ---- B matrices permanently in VGPRs (1 block/CU, 1 wave/SIMD -> ~512 regs OK) ----
    half8 b_z[18], b_p[16];
    {
        const _Float16* bmg = BM16g + ((size_t)ht * 64 + cn) * 576 + kq;
        const _Float16* wtg = WT16g + (size_t)cn * 512 + kq;
        #pragma unroll
        for (int kk = 0; kk < 18; ++kk) b_z[kk] = *(const half8*)(bmg + kk * 32);
        #pragma unroll
        for (int kk = 0; kk < 16; ++kk) b_p[kk] = *(const half8*)(wtg + kk * 32);
    }

    float c_reg = 0.f;          // persistent cell state (row cr, unit cu)
    float lacc = 0.f;           // pred-loss accumulator (wave0 lanes<32)

    // gates + packed-fp16 h store + per-block flag publish
    auto gates_pub = [&](f4 zacc, unsigned* hwu, unsigned tpub) {
        const int prow = (lane >> 4) * 4;
        #pragma unroll
        for (int r = 0; r < 4; ++r) zS[(prow + r) * PSTR + cn] = zacc[r];
        __syncthreads();
        float4 zv = *(const float4*)&zS[cr * PSTR + cu * 4];
        float si = fsig(zv.x + lb0), sf = fsig(zv.y + lb1), so = fsig(zv.w + lb3);
        c_reg = sf * c_reg + si * ftanh(zv.z + lb2);
        float hv = so * ftanh(c_reg);
        float hv1 = __shfl_down(hv, 1);
        if (!(cu & 1)) {
            auto p = __builtin_amdgcn_cvt_pkrtz(hv, hv1);   // __fp16 ext_vector(2)
            coh_st_u(&hwu[(size_t)(r0 + cr) * 256 + ((j0 + cu) >> 1)],
                     __builtin_bit_cast(unsigned, p));
        }
        asm volatile("s_waitcnt vmcnt(0)" ::: "memory");   // this wave's stores are at IC
        __syncthreads();                                   // all 4 waves drained
        if (tid == 0) coh_st_u(&flg[ht], tpub);
    };

    // ---------------- step 0 (t=0): z = x0 @ kernel only (h0=0), write parity 0 ----------------
    {
        const int rr = tid >> 4, dq = (tid & 15) * 4;
        float4 xv = *(const float4*)&x[((size_t)(r0 + rr) * Tt + 0) * Dd + dq];
        half4 xh; xh[0]=(_Float16)xv.x; xh[1]=(_Float16)xv.y; xh[2]=(_Float16)xv.z; xh[3]=(_Float16)xv.w;
        *(half4*)&xinS[rr * XSTR + dq] = xh;
        __syncthreads();
        half8 ax0 = *(const half8*)&xinS[lm * XSTR + kq];
        half8 ax1 = *(const half8*)&xinS[lm * XSTR + 32 + kq];
        f4 zacc = {0.f, 0.f, 0.f, 0.f};
        zacc = __builtin_amdgcn_mfma_f32_16x16x32_f16(ax0, b_z[0], zacc, 0, 0, 0);
        zacc = __builtin_amdgcn_mfma_f32_16x16x32_f16(ax1, b_z[1], zacc, 0, 0, 0);
        gates_pub(zacc, h16u, 1u);
    }

    // ---------------- steps t = 1..255 ----------------
    for (int t = 1; t < Tt; ++t) {
        const _Float16* hr = h16h + ((t - 1) & 1) * (size_t)65536;   // read h[t]
        unsigned*       hwu = h16u + (t & 1) * (size_t)32768;        // write h[t+1]

        // ---- prefetch step-t inputs (off critical path) ----
        const int rr = tid >> 4, dq = (tid & 15) * 4;
        float4 xv = *(const float4*)&x[((size_t)(r0 + rr) * Tt + t) * Dd + dq];
        float tg = 0.f, mkv = 0.f;
        if (wave == 0 && lane < 32) {
            size_t ix = ((size_t)(r0 + (lane & 15)) * (Tt - 1) + (t - 1)) * Dd + 2*ht + (lane >> 4);
            tg = tgt[ix]; mkv = msk[ix];
        }

        // ---- wait for all 32 producer-block flags of h[t] ----
        flag_wait((unsigned)t);

        // ---- cooperative coherent stage: 16 rows x 512 halfs -> LDS (16 KB, once per block)
        // thread tid loads 64 contiguous bytes of global row (tid>>4); replaces the old
        // per-wave 16 KB re-reads (4x less coherent IC traffic).
        {
            const char* hb = (const char*)hr + ((size_t)r0 << 10) + (size_t)tid * 64;
            v4f s0, s1, s2, s3;
            CLD4O(s0, hb, "0"); CLD4O(s1, hb, "16"); CLD4O(s2, hb, "32"); CLD4O(s3, hb, "48");
            CWAIT4(s0, s1, s2, s3);
            _Float16* dst = hS + (size_t)(tid >> 4) * HSTR + (size_t)(tid & 15) * 32;
            *(half8*)(dst)      = __builtin_bit_cast(half8, s0);
            *(half8*)(dst + 8)  = __builtin_bit_cast(half8, s1);
            *(half8*)(dst + 16) = __builtin_bit_cast(half8, s2);
            *(half8*)(dst + 24) = __builtin_bit_cast(half8, s3);
        }
        __syncthreads();

        // ---- per-lane h fragments from LDS (padded stride: b128 bank-floor only) ----
        half8 ah[16];
        {
            const _Float16* hp = hS + (size_t)lm * HSTR + kq;
            #pragma unroll
            for (int j = 0; j < 16; ++j) ah[j] = *(const half8*)(hp + j * 32);
        }

        // ---- pred[16][64] = h @ W^T via MFMA, 2 independent chains (halved dep latency) ----
        {
            f4 p0 = {0.f, 0.f, 0.f, 0.f}, p1 = {0.f, 0.f, 0.f, 0.f};
            #pragma unroll
            for (int kk = 0; kk < 16; kk += 2) {
                p0 = __builtin_amdgcn_mfma_f32_16x16x32_f16(ah[kk],     b_p[kk],     p0, 0, 0, 0);
                p1 = __builtin_amdgcn_mfma_f32_16x16x32_f16(ah[kk + 1], b_p[kk + 1], p1, 0, 0, 0);
            }
            f4 pacc = p0 + p1;
            const int prow = (lane >> 4) * 4;
            #pragma unroll
            for (int r = 0; r < 4; ++r) predS[(prow + r) * PSTR + cn] = pacc[r] + bvp;
        }
        __syncthreads();

        // ---- impute -> xin LDS (fp16); accumulate this block's 2 loss cols ----
        {
            float4 pv = *(const float4*)&predS[rr * PSTR + dq];
            half4 xh;
            xh[0] = (_Float16)((xv.x == MISSINGV) ? pv.x : xv.x);
            xh[1] = (_Float16)((xv.y == MISSINGV) ? pv.y : xv.y);
            xh[2] = (_Float16)((xv.z == MISSINGV) ? pv.z : xv.z);
            xh[3] = (_Float16)((xv.w == MISSINGV) ? pv.w : xv.w);
            *(half4*)&xinS[rr * XSTR + dq] = xh;
            if (wave == 0 && lane < 32) {
                float p = predS[(lane & 15) * PSTR + 2*ht + (lane >> 4)];
                float e = (tg - p) * mkv;
                lacc += e * e;
            }
        }
        __syncthreads();

        // ---- z = [xin | h] @ B : 16 reg-sourced + 2 LDS-sourced MFMAs, 2 chains ----
        {
            half8 ax0 = *(const half8*)&xinS[lm * XSTR + kq];
            half8 ax1 = *(const half8*)&xinS[lm * XSTR + 32 + kq];
            f4 z0 = {0.f, 0.f, 0.f, 0.f}, z1 = {0.f, 0.f, 0.f, 0.f};
            #pragma unroll
            for (int kk = 0; kk < 16; kk += 2) {
                z0 = __builtin_amdgcn_mfma_f32_16x16x32_f16(ah[kk],     b_z[kk + 2], z0, 0, 0, 0);
                z1 = __builtin_amdgcn_mfma_f32_16x16x32_f16(ah[kk + 1], b_z[kk + 3], z1, 0, 0, 0);
            }
            z0 = __builtin_amdgcn_mfma_f32_16x16x32_f16(ax0, b_z[0], z0, 0, 0, 0);
            z1 = __builtin_amdgcn_mfma_f32_16x16x32_f16(ax1, b_z[1], z1, 0, 0, 0);
            gates_pub(z0 + z1, hwu, (unsigned)(t + 1));
        }
    }

    // ---------------- loss reduce; finalize is a separate kernel ----------------
    if (wave == 0) {
        #pragma unroll
        for (int off = 16; off > 0; off >>= 1) lacc += __shfl_down(lacc, off);
        if (lane == 0) atomicAdd(ploss_acc, lacc);
    }
}

// ---------------- finalize: classification + total loss (1 block, 128 threads) ----------------
// Separate dispatch: kernel-boundary ordering makes the persistent kernel's IC-resident
// stores visible to plain cached loads here.
__global__ void finalize(const float* __restrict__ lbl, const float* __restrict__ dW,
                         const float* __restrict__ db, float* __restrict__ out,
                         unsigned char* __restrict__ ws)
{
    __shared__ float dwl[Hh * Cc];
    const int tid = threadIdx.x;
    for (int i = tid; i < Hh * Cc; i += 128) dwl[i] = dW[i];
    __syncthreads();
    const float* ploss_acc = (const float*)(ws + WS_PLOSS);
    const float* reg_acc   = (const float*)(ws + WS_REG);
    const _Float16* h_last = (const _Float16*)(ws + WS_H) + 65536;   // parity 1 (t=255)

    if (tid < Bb) {
        float a[Cc];
        #pragma unroll
        for (int c = 0; c < Cc; ++c) a[c] = db[c];
        const _Float16* hrow = h_last + (size_t)tid * Hh;
        for (int k = 0; k < Hh; k += 8) {
            half8 hh = *(const half8*)(hrow + k);
            #pragma unroll
            for (int j = 0; j < 8; ++j) {
                float hv = (float)hh[j];
                #pragma unroll
                for (int c = 0; c < Cc; ++c) a[c] += hv * dwl[(k + j) * Cc + c];
            }
        }
        float m = a[0];
        #pragma unroll
        for (int c = 1; c < Cc; ++c) m = fmaxf(m, a[c]);
        float s = 0.f;
        #pragma unroll
        for (int c = 0; c < Cc; ++c) s += expf(a[c] - m);
        float lse = m + logf(s);
        float lc = 0.f;
        #pragma unroll
        for (int c = 0; c < Cc; ++c) lc += lbl[tid * Cc + c] * (lse - a[c]);
        float pl = ploss_acc[0];
        float rg = reg_acc[0];
        out[tid] = lc + pl * (1.0f / (2088960.0f * 128.0f)) + 1e-4f * 0.5f * rg;
    }
}

extern "C" void kernel_launch(void* const* d_in, const int* in_sizes, int n_in,
                              void* d_out, int out_size, void* d_ws, size_t ws_size,
                              hipStream_t stream) {
    const float* x     = (const float*)d_in[0];
    const float* tgt   = (const float*)d_in[1];
    const float* msk   = (const float*)d_in[2];
    const float* lbl   = (const float*)d_in[3];
    const float* W     = (const float*)d_in[4];
    const float* bias  = (const float*)d_in[5];
    const float* kern  = (const float*)d_in[6];
    const float* rkern = (const float*)d_in[7];
    const float* lbias = (const float*)d_in[8];
    const float* dW    = (const float*)d_in[9];
    const float* db    = (const float*)d_in[10];
    unsigned char* ws  = (unsigned char*)d_ws;

    (void)hipMemsetAsync(d_ws, 0, 8192, stream);
    prep_weights<<<4608, 256, 0, stream>>>(rkern, kern, W,
                                           (_Float16*)(ws + WS_BM16), (_Float16*)(ws + WS_WT16));
    ajrnn_persistent<<<NBLK, NTHR, 0, stream>>>(x, tgt, msk, W, bias, kern, rkern, lbias,
                                                dW, db, ws);
    finalize<<<1, 128, 0, stream>>>(lbl, dW, db, (float*)d_out, ws);
}

// Round 2
// 729.573 us; speedup vs baseline: 2.7612x; 1.2492x over previous
//
#include <hip/hip_runtime.h>
#include <math.h>

// ---------------- problem dims ----------------
constexpr int Bb = 128, Tt = 256, Dd = 64, Hh = 512, Cc = 10;
constexpr float MISSINGV = 128.0f;

#define NBLK 256
#define NTHR 256

typedef float v4f __attribute__((ext_vector_type(4)));
typedef float f4 __attribute__((ext_vector_type(4)));
typedef _Float16 half8 __attribute__((ext_vector_type(8)));
typedef _Float16 half4 __attribute__((ext_vector_type(4)));

// ---------------- workspace layout (bytes) ----------------
constexpr size_t WS_PLOSS = 128;                    // float pred-loss accumulator
constexpr size_t WS_REG   = 192;                    // float reg accumulator
constexpr size_t WS_FLG   = 256;                    // 8 groups x 512 B per-BLOCK epoch flags (32 words used)
constexpr size_t WS_XC    = 4352;                   // 8 x u32 per-XCD rank counters
constexpr size_t WS_ARR   = 4416;                   // u32 arrival counter
constexpr size_t WS_H     = 8192;                   // h fp16 ping-pong [2][128][512] = 262144 B
constexpr size_t WS_WT16  = WS_H + 262144;          // W^T fp16 [64 d][512 k] = 65536
constexpr size_t WS_BM16  = WS_WT16 + 65536;        // per-ht B fp16 [32][64 n][576 k] = 2359296

// ---------------- LDS layout ----------------
constexpr int XSTR = 72;                            // halfs per xin row (64 + pad)
constexpr int PSTR = 68;                            // floats per predS/zS row
constexpr int HSTR = 520;                           // halfs per hS row (512 + 8 pad)
constexpr size_t SM_XIN  = 0;                       // xin fp16 [16][72] = 2304 B
constexpr size_t SM_PRED = 2304;                    // predS [16][68] f32 = 4352 B
constexpr size_t SM_ZS   = 6656;                    // zS [16][68] f32 = 4352 B
constexpr size_t SM_RED  = 11008;                   // 64 B
constexpr size_t SM_H    = 11072;                   // hS fp16 [16][520] = 16640 B
constexpr size_t SM_TOTAL= SM_H + (size_t)16 * HSTR * 2;   // 27712 B

// ---- coherent vector loads: MALL (sc0 sc1) vs XCD-L2 (sc0, L1-bypass) ----
#define CLD4O_MALL(dst, base, OFF) \
    asm volatile("global_load_dwordx4 %0, %1, off offset:" OFF " sc0 sc1" : "=v"(dst) : "v"(base))
#define CLD4O_L2(dst, base, OFF) \
    asm volatile("global_load_dwordx4 %0, %1, off offset:" OFF " sc0" : "=v"(dst) : "v"(base))
#define CWAIT4(a0,a1,a2,a3) \
    asm volatile("s_waitcnt vmcnt(0)" : "+v"(a0),"+v"(a1),"+v"(a2),"+v"(a3) :: "memory")

// fast, saturation-safe gate functions (abs err ~1e-6, fine vs 5.6e-2 threshold)
__device__ __forceinline__ float fsig(float v)  { return __builtin_amdgcn_rcpf(1.f + __expf(-v)); }
__device__ __forceinline__ float ftanh(float v) { float e = __expf(2.f*v); return 1.f - 2.f*__builtin_amdgcn_rcpf(e+1.f); }

// ---------------- weight prep: fp16 pack ----------------
// WT16[d][k] = W[k][d]; BM16[ht][n][k]: n=u*4+g, col=g*512+ht*16+u;
// k<64 -> kernel[k][col], else rkernel[k-64][col]
__global__ void prep_weights(const float* __restrict__ rk, const float* __restrict__ kern,
                             const float* __restrict__ W,
                             _Float16* __restrict__ bm, _Float16* __restrict__ wt) {
    int o = blockIdx.x * 256 + threadIdx.x;
    if (o < 32 * 64 * 576) {
        int ht = o / 36864, rem = o % 36864, n = rem / 576, k = rem % 576;
        int u = n >> 2, g = n & 3, col = g * 512 + ht * 16 + u;
        float v = (k < 64) ? kern[k * 2048 + col] : rk[(k - 64) * 2048 + col];
        bm[o] = (_Float16)v;
    }
    if (o < 64 * 512) {
        int d = o >> 9, k = o & 511;
        wt[o] = (_Float16)W[k * 64 + d];
    }
}

// ---------------- persistent scan kernel ----------------
__launch_bounds__(NTHR, 1)
__global__ void ajrnn_persistent(
    const float* __restrict__ x, const float* __restrict__ tgt, const float* __restrict__ msk,
    const float* __restrict__ W, const float* __restrict__ bias,
    const float* __restrict__ kern, const float* __restrict__ rkern, const float* __restrict__ lbias,
    const float* __restrict__ dW, const float* __restrict__ db,
    unsigned char* __restrict__ ws)
{
    __shared__ __align__(16) unsigned char smem[SM_TOTAL];
    __shared__ int gS[3];
    _Float16* xinS = (_Float16*)(smem + SM_XIN);
    float* predS = (float*)(smem + SM_PRED);
    float* zS    = (float*)(smem + SM_ZS);
    float* redsc = (float*)(smem + SM_RED);
    _Float16* hS = (_Float16*)(smem + SM_H);

    float* ploss_acc = (float*)(ws + WS_PLOSS);
    float* reg_acc   = (float*)(ws + WS_REG);
    _Float16* h16h   = (_Float16*)(ws + WS_H);      // [2][128][512] halfs
    unsigned* h16u   = (unsigned*)(ws + WS_H);      // same, as packed uints [2][128][256]
    const _Float16* WT16g = (const _Float16*)(ws + WS_WT16);
    const _Float16* BM16g = (const _Float16*)(ws + WS_BM16);

    const int tid = threadIdx.x;
    const int bid = blockIdx.x;
    const int wave = tid >> 6, lane = tid & 63;
    const int lm = lane & 15;                       // MFMA A-row m / B n-within-tile
    const int kq = (lane >> 4) * 8;                 // MFMA quad k offset
    const int cn = wave * 16 + lm;                  // this lane's global col (0..63)
    const int cr = tid >> 4, cu = tid & 15;         // gate-phase row/unit

    // ---- runtime XCD self-organization ----
    // 256 persistent blocks at 1 block/CU => exactly 32 blocks per XCD. Discover the
    // actual placement via HW_REG_XCC_ID; if every XCD has exactly 32 blocks, map
    // row-group rt = XCD id (so the h exchange is coherent through the XCD-local L2,
    // sc0-only) and ht = arrival rank within the XCD. Otherwise fall back to the
    // bid-derived grouping with full-MALL (sc0 sc1) traffic -- never deadlocks.
    {
        unsigned* xcnt = (unsigned*)(ws + WS_XC);
        unsigned* arr  = (unsigned*)(ws + WS_ARR);
        if (tid == 0) {
            unsigned xcc;
            asm volatile("s_getreg_b32 %0, hwreg(HW_REG_XCC_ID)" : "=s"(xcc));
            xcc &= 7u;
            unsigned rk = __hip_atomic_fetch_add(&xcnt[xcc], 1u, __ATOMIC_RELAXED, __HIP_MEMORY_SCOPE_AGENT);
            __hip_atomic_fetch_add(arr, 1u, __ATOMIC_RELEASE, __HIP_MEMORY_SCOPE_AGENT);
            while (__hip_atomic_load(arr, __ATOMIC_ACQUIRE, __HIP_MEMORY_SCOPE_AGENT) < (unsigned)NBLK)
                __builtin_amdgcn_s_sleep(4);
            int ok = 1;
            for (int i = 0; i < 8; ++i)
                ok &= (__hip_atomic_load(&xcnt[i], __ATOMIC_RELAXED, __HIP_MEMORY_SCOPE_AGENT) == 32u);
            gS[0] = (int)xcc; gS[1] = (int)rk; gS[2] = ok;
        }
        __syncthreads();
    }
    const int l2m = gS[2];
    const int rt = l2m ? gS[0] : (bid >> 5);        // 8 row-groups (XCD-local when l2m)
    const int ht = l2m ? gS[1] : (bid & 31);        // 32 hidden-tiles per group
    const int r0 = rt * 16, j0 = ht * 16;

    // ---- per-BLOCK epoch flags (always MALL-coherent: memset zeros are only
    // guaranteed visible via MALL; a stale L2 flag line would silently corrupt).
    // flg[ht] == v  means block (rt,ht) has stored its rows of h[v] (drained) AND
    // finished reading h[v-1].
    unsigned* flg = (unsigned*)(ws + WS_FLG + (size_t)rt * 512);
    auto flag_wait = [&](unsigned t) {
        const unsigned* fp = &flg[lane & 31];
        for (;;) {
            unsigned f;
            asm volatile("global_load_dword %0, %1, off sc0 sc1\n\ts_waitcnt vmcnt(0)"
                         : "=v"(f) : "v"(fp) : "memory");
            if (__all((int)(f >= t))) break;
            __builtin_amdgcn_s_sleep(1);
        }
    };

    // per-thread constants
    const float bvp = bias[cn];
    const int ju = j0 + cu;
    const float lb0 = lbias[ju], lb1 = lbias[Hh + ju], lb2 = lbias[2*Hh + ju], lb3 = lbias[3*Hh + ju];

    // ---- L2 regularization ----
    {
        float rs = 0.f;
        const float* arrs[7] = {W, bias, kern, rkern, lbias, dW, db};
        const int lens[7] = {Hh*Dd, Dd, Dd*4*Hh, Hh*4*Hh, 4*Hh, Hh*Cc, Cc};
        for (int a = 0; a < 7; ++a) {
            const float* p = arrs[a]; const int n = lens[a];
            for (int i = bid * NTHR + tid; i < n; i += NBLK * NTHR) { float v = p[i]; rs += v * v; }
        }
        #pragma unroll
        for (int off = 32; off > 0; off >>= 1) rs += __shfl_down(rs, off);
        if (lane == 0) redsc[wave] = rs;
        __syncthreads();
        if (tid == 0) atomicAdd(reg_acc, redsc[0] + redsc[1] + redsc[2] + redsc[3]);
        __syncthreads();
    }

    // ---- B matrices permanently in VGPRs (1 block/CU, 1 wave/SIMD) ----
    half8 b_z[18], b_p[16];
    {
        const _Float16* bmg = BM16g + ((size_t)ht * 64 + cn) * 576 + kq;
        const _Float16* wtg = WT16g + (size_t)cn * 512 + kq;
        #pragma unroll
        for (int kk = 0; kk < 18; ++kk) b_z[kk] = *(const half8*)(bmg + kk * 32);
        #pragma unroll
        for (int kk = 0; kk < 16; ++kk) b_p[kk] = *(const half8*)(wtg + kk * 32);
    }

    float c_reg = 0.f;          // persistent cell state (row cr, unit cu)
    float lacc = 0.f;           // pred-loss accumulator (wave0 lanes<32)

    // gates + packed-fp16 h store (L2-local when l2m) + per-block flag publish (MALL)
    auto gates_pub = [&](f4 zacc, unsigned* hwu, unsigned tpub) {
        const int prow = (lane >> 4) * 4;
        #pragma unroll
        for (int r = 0; r < 4; ++r) zS[(prow + r) * PSTR + cn] = zacc[r];
        __syncthreads();
        float4 zv = *(const float4*)&zS[cr * PSTR + cu * 4];
        float si = fsig(zv.x + lb0), sf = fsig(zv.y + lb1), so = fsig(zv.w + lb3);
        c_reg = sf * c_reg + si * ftanh(zv.z + lb2);
        float hv = so * ftanh(c_reg);
        float hv1 = __shfl_down(hv, 1);
        if (!(cu & 1)) {
            auto p = __builtin_amdgcn_cvt_pkrtz(hv, hv1);   // __fp16 ext_vector(2)
            unsigned* hp = &hwu[(size_t)(r0 + cr) * 256 + ((j0 + cu) >> 1)];
            unsigned pv = __builtin_bit_cast(unsigned, p);
            if (l2m) asm volatile("global_store_dword %0, %1, off sc0"     :: "v"(hp), "v"(pv) : "memory");
            else     asm volatile("global_store_dword %0, %1, off sc0 sc1" :: "v"(hp), "v"(pv) : "memory");
        }
        asm volatile("s_waitcnt vmcnt(0)" ::: "memory");   // stores committed at coherence point
        __syncthreads();                                   // all 4 waves drained
        if (tid == 0) {
            unsigned* fp = &flg[ht];
            asm volatile("global_store_dword %0, %1, off sc0 sc1" :: "v"(fp), "v"(tpub) : "memory");
        }
    };

    // ---------------- step 0 (t=0): z = x0 @ kernel only (h0=0), write parity 0 ----------------
    {
        const int rr = tid >> 4, dq = (tid & 15) * 4;
        float4 xv = *(const float4*)&x[((size_t)(r0 + rr) * Tt + 0) * Dd + dq];
        half4 xh; xh[0]=(_Float16)xv.x; xh[1]=(_Float16)xv.y; xh[2]=(_Float16)xv.z; xh[3]=(_Float16)xv.w;
        *(half4*)&xinS[rr * XSTR + dq] = xh;
        __syncthreads();
        half8 ax0 = *(const half8*)&xinS[lm * XSTR + kq];
        half8 ax1 = *(const half8*)&xinS[lm * XSTR + 32 + kq];
        f4 zacc = {0.f, 0.f, 0.f, 0.f};
        zacc = __builtin_amdgcn_mfma_f32_16x16x32_f16(ax0, b_z[0], zacc, 0, 0, 0);
        zacc = __builtin_amdgcn_mfma_f32_16x16x32_f16(ax1, b_z[1], zacc, 0, 0, 0);
        gates_pub(zacc, h16u, 1u);
    }

    // ---------------- steps t = 1..255 ----------------
    for (int t = 1; t < Tt; ++t) {
        const _Float16* hr = h16h + ((t - 1) & 1) * (size_t)65536;   // read h[t]
        unsigned*       hwu = h16u + (t & 1) * (size_t)32768;        // write h[t+1]

        // ---- prefetch step-t inputs (off critical path) ----
        const int rr = tid >> 4, dq = (tid & 15) * 4;
        float4 xv = *(const float4*)&x[((size_t)(r0 + rr) * Tt + t) * Dd + dq];
        float tg = 0.f, mkv = 0.f;
        if (wave == 0 && lane < 32) {
            size_t ix = ((size_t)(r0 + (lane & 15)) * (Tt - 1) + (t - 1)) * Dd + 2*ht + (lane >> 4);
            tg = tgt[ix]; mkv = msk[ix];
        }

        // ---- wait for all 32 producer-block flags of h[t] ----
        flag_wait((unsigned)t);

        // ---- cooperative stage: 16 rows x 512 halfs -> LDS (16 KB, once per block)
        {
            const char* hb = (const char*)hr + ((size_t)r0 << 10) + (size_t)tid * 64;
            v4f s0, s1, s2, s3;
            if (l2m) { CLD4O_L2(s0, hb, "0");   CLD4O_L2(s1, hb, "16");
                       CLD4O_L2(s2, hb, "32");  CLD4O_L2(s3, hb, "48"); }
            else     { CLD4O_MALL(s0, hb, "0");  CLD4O_MALL(s1, hb, "16");
                       CLD4O_MALL(s2, hb, "32"); CLD4O_MALL(s3, hb, "48"); }
            CWAIT4(s0, s1, s2, s3);
            _Float16* dst = hS + (size_t)(tid >> 4) * HSTR + (size_t)(tid & 15) * 32;
            *(half8*)(dst)      = __builtin_bit_cast(half8, s0);
            *(half8*)(dst + 8)  = __builtin_bit_cast(half8, s1);
            *(half8*)(dst + 16) = __builtin_bit_cast(half8, s2);
            *(half8*)(dst + 24) = __builtin_bit_cast(half8, s3);
        }
        __syncthreads();

        // ---- per-lane h fragments from LDS ----
        half8 ah[16];
        {
            const _Float16* hp = hS + (size_t)lm * HSTR + kq;
            #pragma unroll
            for (int j = 0; j < 16; ++j) ah[j] = *(const half8*)(hp + j * 32);
        }

        // ---- pred (h @ W^T) and z_h (h @ R) interleaved: 4 independent MFMA chains,
        //      throughput-bound instead of dependent-latency-bound ----
        f4 z0 = {0.f, 0.f, 0.f, 0.f}, z1 = {0.f, 0.f, 0.f, 0.f};
        {
            f4 p0 = {0.f, 0.f, 0.f, 0.f}, p1 = {0.f, 0.f, 0.f, 0.f};
            #pragma unroll
            for (int kk = 0; kk < 16; kk += 2) {
                p0 = __builtin_amdgcn_mfma_f32_16x16x32_f16(ah[kk],     b_p[kk],     p0, 0, 0, 0);
                p1 = __builtin_amdgcn_mfma_f32_16x16x32_f16(ah[kk + 1], b_p[kk + 1], p1, 0, 0, 0);
                z0 = __builtin_amdgcn_mfma_f32_16x16x32_f16(ah[kk],     b_z[kk + 2], z0, 0, 0, 0);
                z1 = __builtin_amdgcn_mfma_f32_16x16x32_f16(ah[kk + 1], b_z[kk + 3], z1, 0, 0, 0);
            }
            f4 pacc = p0 + p1;
            const int prow = (lane >> 4) * 4;
            #pragma unroll
            for (int r = 0; r < 4; ++r) predS[(prow + r) * PSTR + cn] = pacc[r] + bvp;
        }
        __syncthreads();

        // ---- impute -> xin LDS (fp16); accumulate this block's 2 loss cols ----
        {
            float4 pv = *(const float4*)&predS[rr * PSTR + dq];
            half4 xh;
            xh[0] = (_Float16)((xv.x == MISSINGV) ? pv.x : xv.x);
            xh[1] = (_Float16)((xv.y == MISSINGV) ? pv.y : xv.y);
            xh[2] = (_Float16)((xv.z == MISSINGV) ? pv.z : xv.z);
            xh[3] = (_Float16)((xv.w == MISSINGV) ? pv.w : xv.w);
            *(half4*)&xinS[rr * XSTR + dq] = xh;
            if (wave == 0 && lane < 32) {
                float p = predS[(lane & 15) * PSTR + 2*ht + (lane >> 4)];
                float e = (tg - p) * mkv;
                lacc += e * e;
            }
        }
        __syncthreads();

        // ---- z += xin @ K (2 MFMAs) then gates ----
        {
            half8 ax0 = *(const half8*)&xinS[lm * XSTR + kq];
            half8 ax1 = *(const half8*)&xinS[lm * XSTR + 32 + kq];
            z0 = __builtin_amdgcn_mfma_f32_16x16x32_f16(ax0, b_z[0], z0, 0, 0, 0);
            z1 = __builtin_amdgcn_mfma_f32_16x16x32_f16(ax1, b_z[1], z1, 0, 0, 0);
            gates_pub(z0 + z1, hwu, (unsigned)(t + 1));
        }
    }

    // ---------------- loss reduce; finalize is a separate kernel ----------------
    if (wave == 0) {
        #pragma unroll
        for (int off = 16; off > 0; off >>= 1) lacc += __shfl_down(lacc, off);
        if (lane == 0) atomicAdd(ploss_acc, lacc);
    }
}

// ---------------- finalize: classification + total loss (1 block, 128 threads) ----------------
// Separate dispatch: end-of-dispatch release (L2 writeback) makes the persistent
// kernel's stores visible to plain cached loads here.
__global__ void finalize(const float* __restrict__ lbl, const float* __restrict__ dW,
                         const float* __restrict__ db, float* __restrict__ out,
                         unsigned char* __restrict__ ws)
{
    __shared__ float dwl[Hh * Cc];
    const int tid = threadIdx.x;
    for (int i = tid; i < Hh * Cc; i += 128) dwl[i] = dW[i];
    __syncthreads();
    const float* ploss_acc = (const float*)(ws + WS_PLOSS);
    const float* reg_acc   = (const float*)(ws + WS_REG);
    const _Float16* h_last = (const _Float16*)(ws + WS_H) + 65536;   // parity 1 (t=255)

    if (tid < Bb) {
        float a[Cc];
        #pragma unroll
        for (int c = 0; c < Cc; ++c) a[c] = db[c];
        const _Float16* hrow = h_last + (size_t)tid * Hh;
        for (int k = 0; k < Hh; k += 8) {
            half8 hh = *(const half8*)(hrow + k);
            #pragma unroll
            for (int j = 0; j < 8; ++j) {
                float hv = (float)hh[j];
                #pragma unroll
                for (int c = 0; c < Cc; ++c) a[c] += hv * dwl[(k + j) * Cc + c];
            }
        }
        float m = a[0];
        #pragma unroll
        for (int c = 1; c < Cc; ++c) m = fmaxf(m, a[c]);
        float s = 0.f;
        #pragma unroll
        for (int c = 0; c < Cc; ++c) s += expf(a[c] - m);
        float lse = m + logf(s);
        float lc = 0.f;
        #pragma unroll
        for (int c = 0; c < Cc; ++c) lc += lbl[tid * Cc + c] * (lse - a[c]);
        float pl = ploss_acc[0];
        float rg = reg_acc[0];
        out[tid] = lc + pl * (1.0f / (2088960.0f * 128.0f)) + 1e-4f * 0.5f * rg;
    }
}

extern "C" void kernel_launch(void* const* d_in, const int* in_sizes, int n_in,
                              void* d_out, int out_size, void* d_ws, size_t ws_size,
                              hipStream_t stream) {
    const float* x     = (const float*)d_in[0];
    const float* tgt   = (const float*)d_in[1];
    const float* msk   = (const float*)d_in[2];
    const float* lbl   = (const float*)d_in[3];
    const float* W     = (const float*)d_in[4];
    const float* bias  = (const float*)d_in[5];
    const float* kern  = (const float*)d_in[6];
    const float* rkern = (const float*)d_in[7];
    const float* lbias = (const float*)d_in[8];
    const float* dW    = (const float*)d_in[9];
    const float* db    = (const float*)d_in[10];
    unsigned char* ws  = (unsigned char*)d_ws;

    (void)hipMemsetAsync(d_ws, 0, 8192, stream);
    prep_weights<<<4608, 256, 0, stream>>>(rkern, kern, W,
                                           (_Float16*)(ws + WS_BM16), (_Float16*)(ws + WS_WT16));
    ajrnn_persistent<<<NBLK, NTHR, 0, stream>>>(x, tgt, msk, W, bias, kern, rkern, lbias,
                                                dW, db, ws);
    finalize<<<1, 128, 0, stream>>>(lbl, dW, db, (float*)d_out, ws);
}